// Round 8
// baseline (322.694 us; speedup 1.0000x reference)
//
#include <hip/hip_runtime.h>
#include <hip/hip_bf16.h>
#include <math.h>

// GAT 3-layer forward for MI355X.
// R7: attention weights hoisted out of the per-node wave loop into an
// edge-parallel k_weights pass (1 expf per (edge,head) instead of 4; removes
// the csr->as_b dependent gather from the agg loop). Agg inner loop is now
// csr->h only + coalesced w read. Structure otherwise = R6: two-level CSR
// partition, gemm0, [agg+gemm] x2 fused pairwise, agg_final.

#define NEG_SLOPE 0.2f
#define L1_CHUNK 4096

// ---------------- two-level CSR build ----------------

__global__ __launch_bounds__(256) void k_l1hist(
    const int* __restrict__ idx, int* __restrict__ ghist, int E, int etot) {
    __shared__ int h[256];
    const int t = threadIdx.x;
    h[t] = 0;
    __syncthreads();
    const int base = blockIdx.x * L1_CHUNK;
    for (int i = t; i < L1_CHUNK; i += 256) {
        int e = base + i;
        if (e >= etot) break;
        int dst = (e < E) ? idx[E + e] : (e - E);
        atomicAdd(&h[dst >> 8], 1);
    }
    __syncthreads();
    if (h[t]) atomicAdd(&ghist[t], h[t]);
}

__global__ __launch_bounds__(256) void k_scan256(
    const int* __restrict__ ghist, int* __restrict__ goff, int* __restrict__ gcur) {
    __shared__ int sc[256];
    const int t = threadIdx.x;
    int v = ghist[t];
    sc[t] = v;
    __syncthreads();
    for (int o = 1; o < 256; o <<= 1) {
        int x = (t >= o) ? sc[t - o] : 0;
        __syncthreads();
        sc[t] += x;
        __syncthreads();
    }
    int excl = sc[t] - v;
    goff[t] = excl;
    gcur[t] = excl;
    if (t == 255) goff[256] = sc[255];
}

__global__ __launch_bounds__(256) void k_l1scatter(
    const int* __restrict__ idx, int* __restrict__ gcur,
    unsigned long long* __restrict__ buf, int E, int etot) {
    __shared__ int h[256];
    __shared__ int lbase[256];
    const int t = threadIdx.x;
    h[t] = 0;
    __syncthreads();
    const int base = blockIdx.x * L1_CHUNK;
    for (int i = t; i < L1_CHUNK; i += 256) {
        int e = base + i;
        if (e >= etot) break;
        int dst = (e < E) ? idx[E + e] : (e - E);
        atomicAdd(&h[dst >> 8], 1);
    }
    __syncthreads();
    lbase[t] = h[t] ? atomicAdd(&gcur[t], h[t]) : 0;
    __syncthreads();
    h[t] = lbase[t];
    __syncthreads();
    for (int i = t; i < L1_CHUNK; i += 256) {
        int e = base + i;
        if (e >= etot) break;
        int dst, src;
        if (e < E) { dst = idx[E + e]; src = idx[e]; }
        else       { dst = src = e - E; }
        int pos = atomicAdd(&h[dst >> 8], 1);
        buf[pos] = ((unsigned long long)(unsigned)dst << 32) | (unsigned)src;
    }
}

// also emits dstarr[pos] (dst per CSR position) for the k_weights pass
__global__ __launch_bounds__(256) void k_l2build(
    const unsigned long long* __restrict__ buf, const int* __restrict__ goff,
    int* __restrict__ off, int* __restrict__ csr, int* __restrict__ dstarr,
    int n, int etot) {
    __shared__ int sc[256];
    __shared__ int lcur[256];
    const int b = blockIdx.x, t = threadIdx.x;
    const int lo = goff[b], hi = goff[b + 1];
    sc[t] = 0;
    __syncthreads();
    for (int p = lo + t; p < hi; p += 256) {
        int dst = (int)(buf[p] >> 32);
        atomicAdd(&sc[dst & 255], 1);
    }
    __syncthreads();
    int v = sc[t];
    __syncthreads();
    sc[t] = v;
    __syncthreads();
    for (int o = 1; o < 256; o <<= 1) {
        int x = (t >= o) ? sc[t - o] : 0;
        __syncthreads();
        sc[t] += x;
        __syncthreads();
    }
    int excl = sc[t] - v;
    const int d = b * 256 + t;
    if (d < n) off[d] = lo + excl;
    lcur[t] = lo + excl;
    __syncthreads();
    for (int p = lo + t; p < hi; p += 256) {
        unsigned long long e = buf[p];
        int dst = (int)(e >> 32);
        int src = (int)(e & 0xffffffffu);
        int pos = atomicAdd(&lcur[dst & 255], 1);
        csr[pos] = src;
        dstarr[pos] = dst;
    }
    if (b == 0 && t == 0) off[n] = etot;
}

// ---------------- edge-parallel attention weights ----------------
// w[p] = exp(leakyrelu(as[src] + ad[dst])) per head, CSR-ordered.

template <int H>
__global__ __launch_bounds__(256) void k_weights(
    const int* __restrict__ csr, const int* __restrict__ dstarr,
    const float* __restrict__ asb, const float* __restrict__ adb,
    float* __restrict__ wE, int etot) {
    int p = blockIdx.x * 256 + threadIdx.x;
    if (p >= etot) return;
    int s = csr[p], d = dstarr[p];
    if (H == 4) {
        float4 a = *(const float4*)(asb + (size_t)s * 4);
        float4 b = *(const float4*)(adb + (size_t)d * 4);
        float4 ev;
        ev.x = a.x + b.x; ev.y = a.y + b.y; ev.z = a.z + b.z; ev.w = a.w + b.w;
        ev.x = ev.x > 0.f ? ev.x : NEG_SLOPE * ev.x;
        ev.y = ev.y > 0.f ? ev.y : NEG_SLOPE * ev.y;
        ev.z = ev.z > 0.f ? ev.z : NEG_SLOPE * ev.z;
        ev.w = ev.w > 0.f ? ev.w : NEG_SLOPE * ev.w;
        ev.x = __expf(ev.x); ev.y = __expf(ev.y);
        ev.z = __expf(ev.z); ev.w = __expf(ev.w);
        *(float4*)(wE + (size_t)p * 4) = ev;
    } else {
        float ev = asb[s] + adb[d];
        ev = ev > 0.f ? ev : NEG_SLOPE * ev;
        wE[p] = __expf(ev);
    }
}

// ---------------- compute ----------------

// Per-node weighted aggregate using precomputed w. Wave-cooperative:
// quarter q owns edges b+q, b+q+4, ...; lane c4 owns cols 4c4..4c4+3.
// Result valid on q==0 lanes.
template <int H>
__device__ __forceinline__ float4 agg_node(
    const float* __restrict__ h, const float* __restrict__ wE,
    const int* __restrict__ off, const int* __restrict__ csr,
    int node, int q, int c4) {
    const int head = (H == 1) ? 0 : (c4 >> 2);
    const int b = off[node], e = off[node + 1];
    float den = 0.f;
    float4 acc = {0.f, 0.f, 0.f, 0.f};
    int p = b + q;
    int s0 = 0;
    if (p < e) s0 = csr[p];
    while (p < e) {
        const int pn = p + 4;
        int s1 = 0;
        if (pn < e) s1 = csr[pn];                 // prefetch next src
        float wv = (H == 1) ? wE[p] : wE[(size_t)p * 4 + head];
        const float4 hv = *(const float4*)(h + (size_t)s0 * 64 + c4 * 4);
        den += wv;
        acc.x = fmaf(wv, hv.x, acc.x);
        acc.y = fmaf(wv, hv.y, acc.y);
        acc.z = fmaf(wv, hv.z, acc.z);
        acc.w = fmaf(wv, hv.w, acc.w);
        p = pn; s0 = s1;
    }
    den += __shfl_xor(den, 16); den += __shfl_xor(den, 32);
    acc.x += __shfl_xor(acc.x, 16); acc.x += __shfl_xor(acc.x, 32);
    acc.y += __shfl_xor(acc.y, 16); acc.y += __shfl_xor(acc.y, 32);
    acc.z += __shfl_xor(acc.z, 16); acc.z += __shfl_xor(acc.z, 32);
    acc.w += __shfl_xor(acc.w, 16); acc.w += __shfl_xor(acc.w, 32);
    float inv = 1.f / (den + 1e-16f);
    return make_float4(acc.x * inv, acc.y * inv, acc.z * inv, acc.w * inv);
}

// Layer-0 GEMM: h = x @ W0 (K=128/64) + logits. Block = 16 nodes, wave = 4.
template <int K, int H, int F>
__global__ __launch_bounds__(256) void k_gemm_alpha(
    const float* __restrict__ x, const float* __restrict__ W,
    const float* __restrict__ a_s, const float* __restrict__ a_d,
    float* __restrict__ h, float* __restrict__ as_o, float* __restrict__ ad_o,
    int n) {
    __shared__ float xs[16][K];
    const int tid = threadIdx.x;
    const int base = blockIdx.x * 16;
    int rows = n - base; if (rows > 16) rows = 16;
    const int kv = K / 4;
    for (int i = tid; i < rows * kv; i += 256) {
        int r = i / kv, c = i - r * kv;
        ((float4*)&xs[r][0])[c] = ((const float4*)(x + (size_t)(base + r) * K))[c];
    }
    __syncthreads();
    const int w = tid >> 6, lane = tid & 63;
    const int node0 = base + w * 4;
    float acc0 = 0.f, acc1 = 0.f, acc2 = 0.f, acc3 = 0.f;
    #pragma unroll 4
    for (int k = 0; k < K; ++k) {
        float wv = W[k * 64 + lane];
        acc0 = fmaf(xs[w * 4 + 0][k], wv, acc0);
        acc1 = fmaf(xs[w * 4 + 1][k], wv, acc1);
        acc2 = fmaf(xs[w * 4 + 2][k], wv, acc2);
        acc3 = fmaf(xs[w * 4 + 3][k], wv, acc3);
    }
    const int head = (H == 1) ? 0 : (lane >> 4);
    const int f = (H == 1) ? lane : (lane & (F - 1));
    const float asv = a_s[head * F + f];
    const float adv = a_d[head * F + f];
    float accs[4] = {acc0, acc1, acc2, acc3};
    #pragma unroll
    for (int j = 0; j < 4; ++j) {
        int node = node0 + j;
        if (node >= n) break;
        h[(size_t)node * 64 + lane] = accs[j];
        float vs = accs[j] * asv;
        float vd = accs[j] * adv;
        #pragma unroll
        for (int o = F >> 1; o > 0; o >>= 1) {
            vs += __shfl_xor(vs, o);
            vd += __shfl_xor(vd, o);
        }
        if (f == 0) {
            as_o[node * H + head] = vs;
            ad_o[node * H + head] = vd;
        }
    }
}

// Fused agg(layer l) -> +bias -> ELU -> gemm(layer l+1) + logits.
template <int HA, int HG, int FG>
__global__ __launch_bounds__(256) void k_agg_gemm(
    const float* __restrict__ h_in, const float* __restrict__ wE,
    const int* __restrict__ off, const int* __restrict__ csr,
    const float* __restrict__ bias, const float* __restrict__ W,
    const float* __restrict__ a_s, const float* __restrict__ a_d,
    float* __restrict__ h_out, float* __restrict__ asb_out,
    float* __restrict__ adb_out, int n) {
    __shared__ float xs[16][64];
    const int tid = threadIdx.x;
    const int w = tid >> 6, lane = tid & 63;
    const int q = lane >> 4, c4 = lane & 15;
    const int base = blockIdx.x * 16;
    #pragma unroll
    for (int j = 0; j < 4; ++j) {
        const int node = base + w * 4 + j;
        if (node < n) {
            float4 r = agg_node<HA>(h_in, wE, off, csr, node, q, c4);
            if (q == 0) {
                r.x += bias[c4 * 4 + 0]; r.y += bias[c4 * 4 + 1];
                r.z += bias[c4 * 4 + 2]; r.w += bias[c4 * 4 + 3];
                r.x = r.x > 0.f ? r.x : expm1f(r.x);
                r.y = r.y > 0.f ? r.y : expm1f(r.y);
                r.z = r.z > 0.f ? r.z : expm1f(r.z);
                r.w = r.w > 0.f ? r.w : expm1f(r.w);
                *(float4*)&xs[w * 4 + j][c4 * 4] = r;
            }
        }
    }
    __syncthreads();
    float acc0 = 0.f, acc1 = 0.f, acc2 = 0.f, acc3 = 0.f;
    #pragma unroll 4
    for (int k = 0; k < 64; ++k) {
        float wv = W[k * 64 + lane];
        acc0 = fmaf(xs[w * 4 + 0][k], wv, acc0);
        acc1 = fmaf(xs[w * 4 + 1][k], wv, acc1);
        acc2 = fmaf(xs[w * 4 + 2][k], wv, acc2);
        acc3 = fmaf(xs[w * 4 + 3][k], wv, acc3);
    }
    const int head = (HG == 1) ? 0 : (lane >> 4);
    const int f = (HG == 1) ? lane : (lane & (FG - 1));
    const float asv = a_s[head * FG + f];
    const float adv = a_d[head * FG + f];
    float accs[4] = {acc0, acc1, acc2, acc3};
    const int node0 = base + w * 4;
    #pragma unroll
    for (int j = 0; j < 4; ++j) {
        int node = node0 + j;
        if (node >= n) break;
        h_out[(size_t)node * 64 + lane] = accs[j];
        float vs = accs[j] * asv;
        float vd = accs[j] * adv;
        #pragma unroll
        for (int o = FG >> 1; o > 0; o >>= 1) {
            vs += __shfl_xor(vs, o);
            vd += __shfl_xor(vd, o);
        }
        if (f == 0) {
            asb_out[node * HG + head] = vs;
            adb_out[node * HG + head] = vd;
        }
    }
}

// Final aggregate (layer 2, H=1, no ELU) -> d_out. Wave per node.
__global__ __launch_bounds__(256) void k_agg_final(
    const float* __restrict__ h, const float* __restrict__ wE,
    const int* __restrict__ off, const int* __restrict__ csr,
    const float* __restrict__ bias, float* __restrict__ out, int n) {
    const int w = threadIdx.x >> 6, lane = threadIdx.x & 63;
    const int node = blockIdx.x * 4 + w;
    if (node >= n) return;
    const int q = lane >> 4, c4 = lane & 15;
    float4 r = agg_node<1>(h, wE, off, csr, node, q, c4);
    if (q == 0) {
        r.x += bias[c4 * 4 + 0]; r.y += bias[c4 * 4 + 1];
        r.z += bias[c4 * 4 + 2]; r.w += bias[c4 * 4 + 3];
        *(float4*)(out + (size_t)node * 64 + c4 * 4) = r;
    }
}

// ---------------- launch ----------------

extern "C" void kernel_launch(void* const* d_in, const int* in_sizes, int n_in,
                              void* d_out, int out_size, void* d_ws, size_t ws_size,
                              hipStream_t stream) {
    const float* x   = (const float*)d_in[0];
    const int*   idx = (const int*)d_in[1];
    const float* W0  = (const float*)d_in[2];
    const float* as0 = (const float*)d_in[3];
    const float* ad0 = (const float*)d_in[4];
    const float* b0  = (const float*)d_in[5];
    const float* W1  = (const float*)d_in[6];
    const float* as1 = (const float*)d_in[7];
    const float* ad1 = (const float*)d_in[8];
    const float* b1  = (const float*)d_in[9];
    const float* W2  = (const float*)d_in[10];
    const float* as2 = (const float*)d_in[11];
    const float* ad2 = (const float*)d_in[12];
    const float* b2  = (const float*)d_in[13];
    float* out = (float*)d_out;

    const int n    = in_sizes[0] / 128;   // 50000
    const int E    = in_sizes[1] / 2;     // 800000
    const int etot = E + n;

    char* p = (char*)d_ws;
    auto alloc = [&](size_t bytes) {
        char* r = p;
        p += (bytes + 255) & ~(size_t)255;
        return r;
    };
    int*   off    = (int*)alloc((size_t)(n + 1) * 4);
    int*   csr    = (int*)alloc((size_t)etot * 4);
    int*   dstarr = (int*)alloc((size_t)etot * 4);
    int*   ghist  = (int*)alloc(256 * 4);
    int*   goff   = (int*)alloc(257 * 4);
    int*   gcur   = (int*)alloc(256 * 4);
    float* asbA   = (float*)alloc((size_t)n * 4 * 4);
    float* adbA   = (float*)alloc((size_t)n * 4 * 4);
    float* asbB   = (float*)alloc((size_t)n * 4 * 4);
    float* adbB   = (float*)alloc((size_t)n * 4 * 4);
    float* hA     = (float*)alloc((size_t)n * 64 * 4);
    float* hB     = (float*)alloc((size_t)n * 64 * 4);
    float* wE     = (float*)alloc((size_t)etot * 4 * 4);
    // buf (etot*8) aliases wE (etot*16): buf dead after k_l2build, wE first
    // written by k_weights which runs after.
    unsigned long long* buf = (unsigned long long*)wE;

    const int nb_l1 = (etot + L1_CHUNK - 1) / L1_CHUNK;  // 208
    const int nb_l2 = (n + 255) / 256;                   // 196
    const int nb_e  = (etot + 255) / 256;                // 3322
    const int nb_g  = (n + 15) / 16;                     // 3125
    const int nb_w  = (n + 3) / 4;                       // 12500

    // CSR build
    hipMemsetAsync(ghist, 0, 256 * 4, stream);
    k_l1hist<<<nb_l1, 256, 0, stream>>>(idx, ghist, E, etot);
    k_scan256<<<1, 256, 0, stream>>>(ghist, goff, gcur);
    k_l1scatter<<<nb_l1, 256, 0, stream>>>(idx, gcur, buf, E, etot);
    k_l2build<<<nb_l2, 256, 0, stream>>>(buf, goff, off, csr, dstarr, n, etot);

    // layer 0: gemm -> weights -> fused agg+gemm1
    k_gemm_alpha<128, 4, 16><<<nb_g, 256, 0, stream>>>(x, W0, as0, ad0, hA, asbA, adbA, n);
    k_weights<4><<<nb_e, 256, 0, stream>>>(csr, dstarr, asbA, adbA, wE, etot);
    k_agg_gemm<4, 4, 16><<<nb_g, 256, 0, stream>>>(hA, wE, off, csr, b0,
                                                   W1, as1, ad1, hB, asbB, adbB, n);
    // layer 1: weights -> fused agg+gemm2
    k_weights<4><<<nb_e, 256, 0, stream>>>(csr, dstarr, asbB, adbB, wE, etot);
    k_agg_gemm<4, 1, 64><<<nb_g, 256, 0, stream>>>(hB, wE, off, csr, b1,
                                                   W2, as2, ad2, hA, asbA, adbA, n);
    // layer 2: weights -> final agg
    k_weights<1><<<nb_e, 256, 0, stream>>>(csr, dstarr, asbA, adbA, wE, etot);
    k_agg_final<<<nb_w, 256, 0, stream>>>(hA, wE, off, csr, b2, out, n);
}

// Round 9
// 297.067 us; speedup vs baseline: 1.0863x; 1.0863x over previous
//
#include <hip/hip_runtime.h>
#include <hip/hip_bf16.h>
#include <math.h>

// GAT 3-layer forward for MI355X.
// R8: reverted R7's k_weights hoist (cost > benefit; agg is latency-bound,
// not VALU-bound). Agg restructured: 4 nodes per wave aggregated in ONE
// branch-free interleaved loop -> 4 independent csr->h gather chains in
// flight per wave (4x memory-level parallelism). Structure: two-level CSR
// partition, gemm0, [agg+gemm] x2 fused pairwise, agg_final.

#define NEG_SLOPE 0.2f
#define L1_CHUNK 4096

// ---------------- two-level CSR build ----------------

__global__ __launch_bounds__(256) void k_l1hist(
    const int* __restrict__ idx, int* __restrict__ ghist, int E, int etot) {
    __shared__ int h[256];
    const int t = threadIdx.x;
    h[t] = 0;
    __syncthreads();
    const int base = blockIdx.x * L1_CHUNK;
    for (int i = t; i < L1_CHUNK; i += 256) {
        int e = base + i;
        if (e >= etot) break;
        int dst = (e < E) ? idx[E + e] : (e - E);
        atomicAdd(&h[dst >> 8], 1);
    }
    __syncthreads();
    if (h[t]) atomicAdd(&ghist[t], h[t]);
}

__global__ __launch_bounds__(256) void k_scan256(
    const int* __restrict__ ghist, int* __restrict__ goff, int* __restrict__ gcur) {
    __shared__ int sc[256];
    const int t = threadIdx.x;
    int v = ghist[t];
    sc[t] = v;
    __syncthreads();
    for (int o = 1; o < 256; o <<= 1) {
        int x = (t >= o) ? sc[t - o] : 0;
        __syncthreads();
        sc[t] += x;
        __syncthreads();
    }
    int excl = sc[t] - v;
    goff[t] = excl;
    gcur[t] = excl;
    if (t == 255) goff[256] = sc[255];
}

__global__ __launch_bounds__(256) void k_l1scatter(
    const int* __restrict__ idx, int* __restrict__ gcur,
    unsigned long long* __restrict__ buf, int E, int etot) {
    __shared__ int h[256];
    __shared__ int lbase[256];
    const int t = threadIdx.x;
    h[t] = 0;
    __syncthreads();
    const int base = blockIdx.x * L1_CHUNK;
    for (int i = t; i < L1_CHUNK; i += 256) {
        int e = base + i;
        if (e >= etot) break;
        int dst = (e < E) ? idx[E + e] : (e - E);
        atomicAdd(&h[dst >> 8], 1);
    }
    __syncthreads();
    lbase[t] = h[t] ? atomicAdd(&gcur[t], h[t]) : 0;
    __syncthreads();
    h[t] = lbase[t];
    __syncthreads();
    for (int i = t; i < L1_CHUNK; i += 256) {
        int e = base + i;
        if (e >= etot) break;
        int dst, src;
        if (e < E) { dst = idx[E + e]; src = idx[e]; }
        else       { dst = src = e - E; }
        int pos = atomicAdd(&h[dst >> 8], 1);
        buf[pos] = ((unsigned long long)(unsigned)dst << 32) | (unsigned)src;
    }
}

__global__ __launch_bounds__(256) void k_l2build(
    const unsigned long long* __restrict__ buf, const int* __restrict__ goff,
    int* __restrict__ off, int* __restrict__ csr, int n, int etot) {
    __shared__ int sc[256];
    __shared__ int lcur[256];
    const int b = blockIdx.x, t = threadIdx.x;
    const int lo = goff[b], hi = goff[b + 1];
    sc[t] = 0;
    __syncthreads();
    for (int p = lo + t; p < hi; p += 256) {
        int dst = (int)(buf[p] >> 32);
        atomicAdd(&sc[dst & 255], 1);
    }
    __syncthreads();
    int v = sc[t];
    __syncthreads();
    sc[t] = v;
    __syncthreads();
    for (int o = 1; o < 256; o <<= 1) {
        int x = (t >= o) ? sc[t - o] : 0;
        __syncthreads();
        sc[t] += x;
        __syncthreads();
    }
    int excl = sc[t] - v;
    const int d = b * 256 + t;
    if (d < n) off[d] = lo + excl;
    lcur[t] = lo + excl;
    __syncthreads();
    for (int p = lo + t; p < hi; p += 256) {
        unsigned long long e = buf[p];
        int dst = (int)(e >> 32);
        int src = (int)(e & 0xffffffffu);
        int pos = atomicAdd(&lcur[dst & 255], 1);
        csr[pos] = src;
    }
    if (b == 0 && t == 0) off[n] = etot;
}

// ---------------- compute ----------------

// Aggregate FOUR nodes per wave in one branch-free lockstep loop.
// Quarter q owns edges p0+q, p0+q+4, ...; lane c4 owns cols 4c4..4c4+3.
// Each iteration issues 4 independent csr loads + 4 as_b loads + 4 h-row
// loads (clamped addresses, zeroed weights for finished nodes) -> 4 gather
// chains in flight. Results valid on q==0 lanes.
template <int H>
__device__ __forceinline__ void agg_node4(
    const float* __restrict__ h, const float* __restrict__ asb,
    const float* __restrict__ adb, const int* __restrict__ off,
    const int* __restrict__ csr, int node0, int n, int q, int c4,
    float4* res) {
    const int head = (H == 1) ? 0 : (c4 >> 2);
    float den[4] = {0.f, 0.f, 0.f, 0.f};
    float4 acc[4];
    int p[4], e[4];
    float adn[4];
    #pragma unroll
    for (int j = 0; j < 4; ++j) {
        acc[j] = make_float4(0.f, 0.f, 0.f, 0.f);
        const int node = node0 + j;
        if (node < n) {
            p[j] = off[node] + q;
            e[j] = off[node + 1];
            adn[j] = adb[node * H + head];
        } else {
            p[j] = 0; e[j] = 0; adn[j] = 0.f;
        }
    }
    while (p[0] < e[0] || p[1] < e[1] || p[2] < e[2] || p[3] < e[3]) {
        int s[4]; bool valid[4];
        #pragma unroll
        for (int j = 0; j < 4; ++j) {
            valid[j] = p[j] < e[j];
            s[j] = csr[valid[j] ? p[j] : 0];       // safe addr, load issued
        }
        float as_[4];
        #pragma unroll
        for (int j = 0; j < 4; ++j) as_[j] = asb[s[j] * H + head];
        float4 hv[4];
        #pragma unroll
        for (int j = 0; j < 4; ++j)
            hv[j] = *(const float4*)(h + (size_t)s[j] * 64 + c4 * 4);
        #pragma unroll
        for (int j = 0; j < 4; ++j) {
            float ev = as_[j] + adn[j];
            ev = ev > 0.f ? ev : NEG_SLOPE * ev;
            float wv = valid[j] ? __expf(ev) : 0.f;
            den[j] += wv;
            acc[j].x = fmaf(wv, hv[j].x, acc[j].x);
            acc[j].y = fmaf(wv, hv[j].y, acc[j].y);
            acc[j].z = fmaf(wv, hv[j].z, acc[j].z);
            acc[j].w = fmaf(wv, hv[j].w, acc[j].w);
            p[j] += 4;
        }
    }
    #pragma unroll
    for (int j = 0; j < 4; ++j) {
        float d = den[j];
        float4 a = acc[j];
        d += __shfl_xor(d, 16); d += __shfl_xor(d, 32);
        a.x += __shfl_xor(a.x, 16); a.x += __shfl_xor(a.x, 32);
        a.y += __shfl_xor(a.y, 16); a.y += __shfl_xor(a.y, 32);
        a.z += __shfl_xor(a.z, 16); a.z += __shfl_xor(a.z, 32);
        a.w += __shfl_xor(a.w, 16); a.w += __shfl_xor(a.w, 32);
        float inv = 1.f / (d + 1e-16f);
        res[j] = make_float4(a.x * inv, a.y * inv, a.z * inv, a.w * inv);
    }
}

// Layer-0 GEMM: h = x @ W (K=128) + logits. Block = 16 nodes, wave = 4.
template <int K, int H, int F>
__global__ __launch_bounds__(256) void k_gemm_alpha(
    const float* __restrict__ x, const float* __restrict__ W,
    const float* __restrict__ a_s, const float* __restrict__ a_d,
    float* __restrict__ h, float* __restrict__ as_o, float* __restrict__ ad_o,
    int n) {
    __shared__ float xs[16][K];
    const int tid = threadIdx.x;
    const int base = blockIdx.x * 16;
    int rows = n - base; if (rows > 16) rows = 16;
    const int kv = K / 4;
    for (int i = tid; i < rows * kv; i += 256) {
        int r = i / kv, c = i - r * kv;
        ((float4*)&xs[r][0])[c] = ((const float4*)(x + (size_t)(base + r) * K))[c];
    }
    __syncthreads();
    const int w = tid >> 6, lane = tid & 63;
    const int node0 = base + w * 4;
    float acc0 = 0.f, acc1 = 0.f, acc2 = 0.f, acc3 = 0.f;
    #pragma unroll 4
    for (int k = 0; k < K; ++k) {
        float wv = W[k * 64 + lane];
        acc0 = fmaf(xs[w * 4 + 0][k], wv, acc0);
        acc1 = fmaf(xs[w * 4 + 1][k], wv, acc1);
        acc2 = fmaf(xs[w * 4 + 2][k], wv, acc2);
        acc3 = fmaf(xs[w * 4 + 3][k], wv, acc3);
    }
    const int head = (H == 1) ? 0 : (lane >> 4);
    const int f = (H == 1) ? lane : (lane & (F - 1));
    const float asv = a_s[head * F + f];
    const float adv = a_d[head * F + f];
    float accs[4] = {acc0, acc1, acc2, acc3};
    #pragma unroll
    for (int j = 0; j < 4; ++j) {
        int node = node0 + j;
        if (node >= n) break;
        h[(size_t)node * 64 + lane] = accs[j];
        float vs = accs[j] * asv;
        float vd = accs[j] * adv;
        #pragma unroll
        for (int o = F >> 1; o > 0; o >>= 1) {
            vs += __shfl_xor(vs, o);
            vd += __shfl_xor(vd, o);
        }
        if (f == 0) {
            as_o[node * H + head] = vs;
            ad_o[node * H + head] = vd;
        }
    }
}

// Fused agg(layer l) -> +bias -> ELU -> gemm(layer l+1) + logits.
template <int HA, int HG, int FG>
__global__ __launch_bounds__(256) void k_agg_gemm(
    const float* __restrict__ h_in, const float* __restrict__ asb_in,
    const float* __restrict__ adb_in, const int* __restrict__ off,
    const int* __restrict__ csr, const float* __restrict__ bias,
    const float* __restrict__ W, const float* __restrict__ a_s,
    const float* __restrict__ a_d, float* __restrict__ h_out,
    float* __restrict__ asb_out, float* __restrict__ adb_out, int n) {
    __shared__ float xs[16][64];
    const int tid = threadIdx.x;
    const int w = tid >> 6, lane = tid & 63;
    const int q = lane >> 4, c4 = lane & 15;
    const int base = blockIdx.x * 16;
    float4 res[4];
    agg_node4<HA>(h_in, asb_in, adb_in, off, csr, base + w * 4, n, q, c4, res);
    if (q == 0) {
        #pragma unroll
        for (int j = 0; j < 4; ++j) {
            if (base + w * 4 + j < n) {
                float4 r = res[j];
                r.x += bias[c4 * 4 + 0]; r.y += bias[c4 * 4 + 1];
                r.z += bias[c4 * 4 + 2]; r.w += bias[c4 * 4 + 3];
                r.x = r.x > 0.f ? r.x : expm1f(r.x);
                r.y = r.y > 0.f ? r.y : expm1f(r.y);
                r.z = r.z > 0.f ? r.z : expm1f(r.z);
                r.w = r.w > 0.f ? r.w : expm1f(r.w);
                *(float4*)&xs[w * 4 + j][c4 * 4] = r;
            }
        }
    }
    __syncthreads();
    float acc0 = 0.f, acc1 = 0.f, acc2 = 0.f, acc3 = 0.f;
    #pragma unroll 4
    for (int k = 0; k < 64; ++k) {
        float wv = W[k * 64 + lane];
        acc0 = fmaf(xs[w * 4 + 0][k], wv, acc0);
        acc1 = fmaf(xs[w * 4 + 1][k], wv, acc1);
        acc2 = fmaf(xs[w * 4 + 2][k], wv, acc2);
        acc3 = fmaf(xs[w * 4 + 3][k], wv, acc3);
    }
    const int head = (HG == 1) ? 0 : (lane >> 4);
    const int f = (HG == 1) ? lane : (lane & (FG - 1));
    const float asv = a_s[head * FG + f];
    const float adv = a_d[head * FG + f];
    float accs[4] = {acc0, acc1, acc2, acc3};
    const int node0 = base + w * 4;
    #pragma unroll
    for (int j = 0; j < 4; ++j) {
        int node = node0 + j;
        if (node >= n) break;
        h_out[(size_t)node * 64 + lane] = accs[j];
        float vs = accs[j] * asv;
        float vd = accs[j] * adv;
        #pragma unroll
        for (int o = FG >> 1; o > 0; o >>= 1) {
            vs += __shfl_xor(vs, o);
            vd += __shfl_xor(vd, o);
        }
        if (f == 0) {
            asb_out[node * HG + head] = vs;
            adb_out[node * HG + head] = vd;
        }
    }
}

// Final aggregate (layer 2, H=1, no ELU) -> d_out. Block = 16 nodes.
__global__ __launch_bounds__(256) void k_agg_final(
    const float* __restrict__ h, const float* __restrict__ asb,
    const float* __restrict__ adb, const int* __restrict__ off,
    const int* __restrict__ csr, const float* __restrict__ bias,
    float* __restrict__ out, int n) {
    const int tid = threadIdx.x;
    const int w = tid >> 6, lane = tid & 63;
    const int q = lane >> 4, c4 = lane & 15;
    const int base = blockIdx.x * 16;
    float4 res[4];
    agg_node4<1>(h, asb, adb, off, csr, base + w * 4, n, q, c4, res);
    if (q == 0) {
        #pragma unroll
        for (int j = 0; j < 4; ++j) {
            const int node = base + w * 4 + j;
            if (node < n) {
                float4 r = res[j];
                r.x += bias[c4 * 4 + 0]; r.y += bias[c4 * 4 + 1];
                r.z += bias[c4 * 4 + 2]; r.w += bias[c4 * 4 + 3];
                *(float4*)(out + (size_t)node * 64 + c4 * 4) = r;
            }
        }
    }
}

// ---------------- launch ----------------

extern "C" void kernel_launch(void* const* d_in, const int* in_sizes, int n_in,
                              void* d_out, int out_size, void* d_ws, size_t ws_size,
                              hipStream_t stream) {
    const float* x   = (const float*)d_in[0];
    const int*   idx = (const int*)d_in[1];
    const float* W0  = (const float*)d_in[2];
    const float* as0 = (const float*)d_in[3];
    const float* ad0 = (const float*)d_in[4];
    const float* b0  = (const float*)d_in[5];
    const float* W1  = (const float*)d_in[6];
    const float* as1 = (const float*)d_in[7];
    const float* ad1 = (const float*)d_in[8];
    const float* b1  = (const float*)d_in[9];
    const float* W2  = (const float*)d_in[10];
    const float* as2 = (const float*)d_in[11];
    const float* ad2 = (const float*)d_in[12];
    const float* b2  = (const float*)d_in[13];
    float* out = (float*)d_out;

    const int n    = in_sizes[0] / 128;   // 50000
    const int E    = in_sizes[1] / 2;     // 800000
    const int etot = E + n;

    char* p = (char*)d_ws;
    auto alloc = [&](size_t bytes) {
        char* r = p;
        p += (bytes + 255) & ~(size_t)255;
        return r;
    };
    int*   off   = (int*)alloc((size_t)(n + 1) * 4);
    int*   csr   = (int*)alloc((size_t)etot * 4);
    int*   ghist = (int*)alloc(256 * 4);
    int*   goff  = (int*)alloc(257 * 4);
    int*   gcur  = (int*)alloc(256 * 4);
    float* asbA  = (float*)alloc((size_t)n * 4 * 4);
    float* adbA  = (float*)alloc((size_t)n * 4 * 4);
    float* asbB  = (float*)alloc((size_t)n * 4 * 4);
    float* adbB  = (float*)alloc((size_t)n * 4 * 4);
    float* hA    = (float*)alloc((size_t)n * 64 * 4);
    float* hB    = (float*)alloc((size_t)n * 64 * 4);
    // buf (etot*8 = 6.8 MB) aliases hB: buf dead after k_l2build, hB first
    // written by the first k_agg_gemm (later in stream order).
    unsigned long long* buf = (unsigned long long*)hB;

    const int nb_l1 = (etot + L1_CHUNK - 1) / L1_CHUNK;  // 208
    const int nb_l2 = (n + 255) / 256;                   // 196
    const int nb_g  = (n + 15) / 16;                     // 3125

    // CSR build
    hipMemsetAsync(ghist, 0, 256 * 4, stream);
    k_l1hist<<<nb_l1, 256, 0, stream>>>(idx, ghist, E, etot);
    k_scan256<<<1, 256, 0, stream>>>(ghist, goff, gcur);
    k_l1scatter<<<nb_l1, 256, 0, stream>>>(idx, gcur, buf, E, etot);
    k_l2build<<<nb_l2, 256, 0, stream>>>(buf, goff, off, csr, n, etot);

    // layer 0 GEMM: x(128) -> hA, logits A
    k_gemm_alpha<128, 4, 16><<<nb_g, 256, 0, stream>>>(x, W0, as0, ad0, hA, asbA, adbA, n);
    // agg0 (+b0, ELU) -> gemm1 -> hB, logits B
    k_agg_gemm<4, 4, 16><<<nb_g, 256, 0, stream>>>(hA, asbA, adbA, off, csr, b0,
                                                   W1, as1, ad1, hB, asbB, adbB, n);
    // agg1 (+b1, ELU) -> gemm2 -> hA, logits A
    k_agg_gemm<4, 1, 64><<<nb_g, 256, 0, stream>>>(hB, asbB, adbB, off, csr, b1,
                                                   W2, as2, ad2, hA, asbA, adbA, n);
    // agg2 (+b2) -> out
    k_agg_final<<<nb_g, 256, 0, stream>>>(hA, asbA, adbA, off, csr, b2, out, n);
}